// Round 4
// baseline (271.331 us; speedup 1.0000x reference)
//
#include <hip/hip_runtime.h>
#include <hip/hip_bf16.h>
#include <math.h>

// Shapes
#define NN 64
#define CC 64
#define TT 256
#define VV 25
#define DD 64
#define BN_EPS 1e-5f
#define NREP 16

typedef short bf16x8 __attribute__((ext_vector_type(8)));
typedef float f32x4 __attribute__((ext_vector_type(4)));

// ws layout (float offsets)
#define WS_POOLED 0            // [64][64]
#define WS_GATE   4096         // [64][4]
#define WS_BFUSE  4352         // [64][64]
#define WS_MASK   8448         // [25][64] f32 linear
#define WS_ABP    10048        // u32[1600] packed (a=lo16, b=hi16) bf16
#define WS_S1     13248        // [16][1600] replicas (memset 0)
#define WS_S2     38848        // [16][1600]
#define WS_WTB    64448        // ushort[64][64][64] fused W^T bf16

static __device__ __forceinline__ unsigned short f2bf(float x) {
    __hip_bfloat16 h = __float2bfloat16(x);
    return *(unsigned short*)&h;
}

// ---------------- K0: global average pool over (T,V) ----------------
__global__ __launch_bounds__(256) void k_pool(const float* __restrict__ x0,
                                              float* __restrict__ pooled) {
    __shared__ float red[256];
    const int bid = blockIdx.x;                // n*64 + c
    const float4* p = (const float4*)(x0 + (size_t)bid * (TT * VV));
    float s = 0.f;
    for (int k = threadIdx.x; k < (TT * VV) / 4; k += 256) {
        float4 v = p[k];
        s += v.x + v.y + v.z + v.w;
    }
    red[threadIdx.x] = s;
    __syncthreads();
    for (int off = 128; off > 0; off >>= 1) {
        if (threadIdx.x < off) red[threadIdx.x] += red[threadIdx.x + off];
        __syncthreads();
    }
    if (threadIdx.x == 0) pooled[bid] = red[0] * (1.f / (TT * VV));
}

// ---------------- K1: gate MLP + softmax, bfuse, mask ----------------
__global__ __launch_bounds__(256) void k_gate(const float* __restrict__ fc1_w,
                                              const float* __restrict__ fc1_b,
                                              const float* __restrict__ fc2_w,
                                              const float* __restrict__ fc2_b,
                                              const float* __restrict__ lin_b,
                                              const float* __restrict__ fmask,
                                              const int* __restrict__ epoch_p,
                                              float* ws) {
    const int tid = threadIdx.x;
    float* pooled = ws + WS_POOLED;
    float* gate   = ws + WS_GATE;
    float* bfuse  = ws + WS_BFUSE;
    float* mask   = ws + WS_MASK;

    if (tid < 64) {
        const int n = tid;
        const float* po = pooled + n * 64;
        float h[16];
        for (int q = 0; q < 16; q++) {
            float z = fc1_b[q];
            for (int j = 0; j < 64; j++) z = fmaf(fc1_w[q * 64 + j], po[j], z);
            h[q] = fmaxf(z, 0.f);
        }
        float lg[4];
        for (int k = 0; k < 4; k++) {
            float z = fc2_b[k];
            for (int q = 0; q < 16; q++) z = fmaf(fc2_w[k * 16 + q], h[q], z);
            lg[k] = z;
        }
        const int ep = epoch_p[0];
        const float tao = (ep < 60) ? (-(29.0f / 60.0f) * (float)ep + 30.0f) : 1.0f;
        float mx = -1e30f;
        for (int k = 0; k < 4; k++) { lg[k] /= tao; mx = fmaxf(mx, lg[k]); }
        float se = 0.f;
        for (int k = 0; k < 4; k++) { lg[k] = expf(lg[k] - mx); se += lg[k]; }
        const float inv = 1.f / se;
        for (int k = 0; k < 4; k++) gate[n * 4 + k] = lg[k] * inv;
    }
    __syncthreads();
    for (int f = tid; f < 4096; f += 256) {
        const int n = f >> 6, d = f & 63;
        float s = 0.f;
        for (int k = 0; k < 4; k++) s = fmaf(lin_b[k * 64 + d], gate[n * 4 + k], s);
        bfuse[f] = s;
    }
    for (int f = tid; f < VV * CC; f += 256) mask[f] = tanhf(fmask[f]) + 1.0f;
}

// ---------------- K1b: fused weight, transposed, bf16: Wtb[n][d][c] ----------------
__global__ __launch_bounds__(256) void k_wfuse(const float* __restrict__ lw, float* ws) {
    __shared__ float tile[64 * 65];
    const float* gate = ws + WS_GATE;
    unsigned short* wtb = (unsigned short*)(ws + WS_WTB);
    const int n = blockIdx.x;
    float g[4];
    for (int k = 0; k < 4; k++) g[k] = gate[n * 4 + k];
    for (int f = threadIdx.x; f < 4096; f += 256) {
        const int c = f >> 6, d = f & 63;
        float v = g[0] * lw[f] + g[1] * lw[4096 + f] + g[2] * lw[8192 + f] + g[3] * lw[12288 + f];
        tile[d * 65 + c] = v;
    }
    __syncthreads();
    for (int f = threadIdx.x; f < 4096; f += 256) {
        const int d = f >> 6, c = f & 63;
        wtb[n * 4096 + f] = f2bf(tile[d * 65 + c]);
    }
}

// ---------------- K3: finalize BN -> packed bf16 (scale, shift) per out-feature ----------------
__global__ __launch_bounds__(256) void k_finalize(const float* __restrict__ gamma,
                                                  const float* __restrict__ beta,
                                                  float* ws) {
    const int f = blockIdx.x * 256 + threadIdx.x;   // out-feature v*64+d
    if (f >= VV * DD) return;
    const int v = f >> 6, d = f & 63;
    const int vi = (v - d + 175) % 25;              // source (unshifted) v index
    const int fin = vi * 64 + d;
    float s1 = 0.f, s2 = 0.f;
    for (int rep = 0; rep < NREP; rep++) {
        s1 += ws[WS_S1 + rep * 1600 + fin];
        s2 += ws[WS_S2 + rep * 1600 + fin];
    }
    const float mean = s1 * (1.f / (NN * TT));
    float var = s2 * (1.f / (NN * TT)) - mean * mean;
    var = fmaxf(var, 0.f);
    const float rs = rsqrtf(var + BN_EPS);
    const float a = gamma[f] * rs;
    const float b = beta[f] - mean * a;
    const unsigned pa = (unsigned)f2bf(a);
    const unsigned pb = (unsigned)f2bf(b);
    ((unsigned*)ws)[WS_ABP + f] = pa | (pb << 16);
}

// ---------------- K2/K4: main per-sample GEMM via bf16 MFMA ----------------
// PHASE 0: grid (16,64), 4 chunks of 100 rows; A=Xm,B=W; stats in regs -> LDS -> global atomics.
// PHASE 1: grid (32,64), 2 chunks; SWAPPED operands (A=W,B=Xm) -> acc cols = tv -> direct
//          semi-coalesced stores with BN + shift-out + residual + relu (no outl buffer).
template <int PHASE>
__global__ __launch_bounds__(256, 4) void k_main(const float* __restrict__ x0,
                                                 const unsigned short* __restrict__ wtb,
                                                 const float* __restrict__ ws,
                                                 float* __restrict__ wsmut,
                                                 float* __restrict__ out) {
    constexpr int LDSZ = (PHASE == 0) ? 31856 : 38656;
    __shared__ __align__(16) char pool[LDSZ];
    unsigned short (*Wl)[72] = (unsigned short(*)[72])(pool);          // 9216 B
    float* maskL = (float*)(pool + 9216);                              // [25][65] 6500 B
    unsigned short (*Xm)[72] = (unsigned short(*)[72])(pool + 15728);  // [112][72] 16128 B
    unsigned* ABl = (unsigned*)(pool + 31856);                         // P1: [25][68] u32

    const int n = blockIdx.y, tb = blockIdx.x;
    const int tid = threadIdx.x;
    const int wv = tid >> 6, lane = tid & 63;
    const int lrow = lane & 15, lgrp = lane >> 4;
    const int dcol = wv * 16 + lrow;
    constexpr int NCK = (PHASE == 0) ? 4 : 2;
    const int colbase = tb * 100 * NCK;

    // ---- one-time staging ----
    {
        const uint4* wsrc = (const uint4*)(wtb + n * 4096);
        for (int it = tid; it < 512; it += 256) {
            uint4 u = wsrc[it];
            const int f8 = it * 8;
            *(uint4*)&Wl[f8 >> 6][f8 & 63] = u;
        }
        for (int f = tid; f < 1600; f += 256)
            maskL[(f >> 6) * 65 + (f & 63)] = ws[WS_MASK + f];
        // zero Xm pad rows 100..111 (read by MFMA, results discarded)
        for (int f = tid; f < 864; f += 256) ((unsigned short*)Xm)[7200 + f] = 0;
        if (PHASE == 1) {
            const unsigned* abp = (const unsigned*)(ws + WS_ABP);
            for (int f = tid; f < 1600; f += 256)
                ABl[(f >> 6) * 68 + (f & 63)] = abp[f];
        }
    }
    const float bfv = ws[WS_BFUSE + n * 64 + dcol];
    f32x4 bias4;
    if (PHASE == 1) {
        const float4 b4 = *(const float4*)&ws[WS_BFUSE + n * 64 + wv * 16 + 4 * lgrp];
        bias4[0] = b4.x; bias4[1] = b4.y; bias4[2] = b4.z; bias4[3] = b4.w;
    }
    __syncthreads();

    const bf16x8 w0 = *(const bf16x8*)&Wl[dcol][8 * lgrp];
    const bf16x8 w1 = *(const bf16x8*)&Wl[dcol][32 + 8 * lgrp];

    float s1r[7][4], s2r[7][4];
    if (PHASE == 0) {
#pragma unroll
        for (int m = 0; m < 7; m++)
#pragma unroll
            for (int r = 0; r < 4; r++) { s1r[m][r] = 0.f; s2r[m][r] = 0.f; }
    }

    const size_t nbase = (size_t)n * (CC * TT * VV);

    for (int ck = 0; ck < NCK; ck++) {
        const int gcol0 = colbase + ck * 100;
        if (ck) __syncthreads();      // prior chunk's MFMA reads must finish
        // ---- stage X chunk: float4 loads, shift-in gather + mask, f32->bf16 ----
        for (int l4 = tid; l4 < 1600; l4 += 256) {
            const int j = l4 / 25, q = l4 - j * 25;
            const float4 xv = *(const float4*)(x0 + nbase + j * 6400 + gcol0 + q * 4);
            int jm = j; if (jm >= 50) jm -= 50; else if (jm >= 25) jm -= 25;
            const float xe[4] = {xv.x, xv.y, xv.z, xv.w};
#pragma unroll
            for (int e = 0; e < 4; e++) {
                const int r = q * 4 + e;
                const int trel = (r >= 75) ? 3 : (r >= 50) ? 2 : (r >= 25) ? 1 : 0;
                const int p = r - trel * 25;
                int i = p - jm; if (i < 0) i += 25;
                Xm[trel * 25 + i][j] = f2bf(xe[e] * maskL[i * 65 + j]);
            }
        }
        __syncthreads();

        if (PHASE == 0) {
            // A = Xm rows (tv), B = W rows (d): acc rows = tv, cols = d
#pragma unroll
            for (int m = 0; m < 7; m++) {
                f32x4 a = {bfv, bfv, bfv, bfv};
                const bf16x8 a0 = *(const bf16x8*)&Xm[m * 16 + lrow][8 * lgrp];
                const bf16x8 a1 = *(const bf16x8*)&Xm[m * 16 + lrow][32 + 8 * lgrp];
                a = __builtin_amdgcn_mfma_f32_16x16x32_bf16(a0, w0, a, 0, 0, 0);
                a = __builtin_amdgcn_mfma_f32_16x16x32_bf16(a1, w1, a, 0, 0, 0);
#pragma unroll
                for (int r = 0; r < 4; r++) {
                    const int row = m * 16 + 4 * lgrp + r;
                    if (row < 100) {
                        const float y = a[r];
                        s1r[m][r] += y;
                        s2r[m][r] = fmaf(y, y, s2r[m][r]);
                    }
                }
            }
        } else {
            // SWAPPED: A = W rows (d), B = Xm rows (tv): acc rows = d, cols = tv
            f32x4 acc[7];
#pragma unroll
            for (int tvt = 0; tvt < 7; tvt++) {
                f32x4 a = bias4;
                const bf16x8 xb0 = *(const bf16x8*)&Xm[tvt * 16 + lrow][8 * lgrp];
                const bf16x8 xb1 = *(const bf16x8*)&Xm[tvt * 16 + lrow][32 + 8 * lgrp];
                a = __builtin_amdgcn_mfma_f32_16x16x32_bf16(w0, xb0, a, 0, 0, 0);
                a = __builtin_amdgcn_mfma_f32_16x16x32_bf16(w1, xb1, a, 0, 0, 0);
                acc[tvt] = a;
            }
            const int dB = wv * 16 + 4 * lgrp;
#pragma unroll
            for (int tvt = 0; tvt < 7; tvt++) {
                const int rloc = tvt * 16 + lrow;
                if (rloc < 100) {
                    const int grow = gcol0 + rloc;
                    const int t = grow / 25;
                    const int v = grow - t * 25;
                    const int vv0 = v + dB;
#pragma unroll
                    for (int r = 0; r < 4; r++) {
                        int vo = vv0 + r;
                        if (vo >= 75) vo -= 75; else if (vo >= 50) vo -= 50; else if (vo >= 25) vo -= 25;
                        const int d = dB + r;
                        const unsigned u = ABl[vo * 68 + d];
                        const float a_ = __uint_as_float(u << 16);
                        const float b_ = __uint_as_float(u & 0xffff0000u);
                        const size_t off = nbase + (size_t)d * 6400 + t * 25 + vo;
                        const float val = fmaf(a_, acc[tvt][r], b_) + x0[off];
                        out[off] = fmaxf(val, 0.f);
                    }
                }
            }
        }
    }

    if (PHASE == 0) {
        __syncthreads();                          // Xm dead; reuse as stats
        float* s1l = (float*)(pool + 15728);      // [25][66]
        float* s2l = s1l + 1650;
        for (int f = tid; f < 3300; f += 256) s1l[f] = 0.f;
        __syncthreads();
#pragma unroll
        for (int m = 0; m < 7; m++) {
#pragma unroll
            for (int r = 0; r < 4; r++) {
                const int row = m * 16 + 4 * lgrp + r;
                if (row < 100) {
                    int v = row;
                    if (v >= 75) v -= 75; else if (v >= 50) v -= 50; else if (v >= 25) v -= 25;
                    __hip_atomic_fetch_add(&s1l[v * 66 + dcol], s1r[m][r],
                                           __ATOMIC_RELAXED, __HIP_MEMORY_SCOPE_WORKGROUP);
                    __hip_atomic_fetch_add(&s2l[v * 66 + dcol], s2r[m][r],
                                           __ATOMIC_RELAXED, __HIP_MEMORY_SCOPE_WORKGROUP);
                }
            }
        }
        __syncthreads();
        const int rep = (n * 5 + tb) & (NREP - 1);
        float* g1 = wsmut + WS_S1 + rep * 1600;
        float* g2 = wsmut + WS_S2 + rep * 1600;
        for (int f = tid; f < 1600; f += 256) {
            atomicAdd(&g1[f], s1l[(f >> 6) * 66 + (f & 63)]);
            atomicAdd(&g2[f], s2l[(f >> 6) * 66 + (f & 63)]);
        }
    }
}

extern "C" void kernel_launch(void* const* d_in, const int* in_sizes, int n_in,
                              void* d_out, int out_size, void* d_ws, size_t ws_size,
                              hipStream_t stream) {
    const float* x0    = (const float*)d_in[0];
    const float* fc1_w = (const float*)d_in[1];
    const float* fc1_b = (const float*)d_in[2];
    const float* fc2_w = (const float*)d_in[3];
    const float* fc2_b = (const float*)d_in[4];
    const float* lw    = (const float*)d_in[5];
    const float* lb    = (const float*)d_in[6];
    const float* fmask = (const float*)d_in[7];
    const float* gamma = (const float*)d_in[8];
    const float* beta  = (const float*)d_in[9];
    const int* epoch   = (const int*)d_in[12];
    float* ws  = (float*)d_ws;
    float* out = (float*)d_out;
    const unsigned short* wtb = (const unsigned short*)(ws + WS_WTB);

    k_pool<<<NN * CC, 256, 0, stream>>>(x0, ws + WS_POOLED);
    k_gate<<<1, 256, 0, stream>>>(fc1_w, fc1_b, fc2_w, fc2_b, lb, fmask, epoch, ws);
    k_wfuse<<<NN, 256, 0, stream>>>(lw, ws);
    hipMemsetAsync((char*)d_ws + WS_S1 * sizeof(float), 0, (size_t)NREP * 3200 * sizeof(float), stream);

    k_main<0><<<dim3(16, 64), 256, 0, stream>>>(x0, wtb, ws, ws, out);
    k_finalize<<<7, 256, 0, stream>>>(gamma, beta, ws);
    k_main<1><<<dim3(32, 64), 256, 0, stream>>>(x0, wtb, ws, ws, out);
}